// Round 5
// baseline (93.753 us; speedup 1.0000x reference)
//
#include <hip/hip_runtime.h>
#include <math.h>

#define TBINS   50000
#define NR      5
#define RBINS   10000          // TBINS / NR
#define GROUP   256
#define NGROUPS 196            // ceil(TBINS / GROUP)
#define EPSF    1e-7f
#define PTHR    1024
#define STRIDE  (PTHR * 8)
#define MAXNS   104
#define MAXNB   (NR * 128)

// ---- fixed ws layout (byte offsets) ----
#define OFF_ALLG  0            // f32[TBINS]
#define OFF_EVG   200000       // f32[TBINS] (decoded D)
#define OFF_CNTG  400000       // i32[TBINS]
#define OFF_GSUM  600000       // f32[NGROUPS] (pad 800)
#define OFF_SCAL  600800       // dbl[2]
#define OFF_NEV   600816       // int (pad to 600832)
#define OFF_LRP   600832       // f32[MAXNB]
#define OFF_NP    603392       // i32[MAXNB]
#define OFF_SLICE 605952       // per slice: f32 wa[TBINS] + u32 wec[TBINS]
#define PER_SLICE 400000

// ---------------- histogram pass: LDS-privatized, XCD-swizzled, 2 blocks/CU ----------------
__global__ __launch_bounds__(PTHR, 8) void k_pass(
        const float* __restrict__ lr, const int* __restrict__ tm,
        const int* __restrict__ ev, int N, int NS, int CH, char* ws) {
    __shared__ float    s_all[RBINS];
    __shared__ unsigned s_evcnt[RBINS];   // (count<<28) | fixed12.16(sum exp over events)
    __shared__ float    red_f[16];
    __shared__ int      red_i[16];

    int bid = blockIdx.x;
    int range, slice;
    if ((NS & 7) == 0) {
        // XCD-aware: hw assigns XCD = bid % 8; co-locate a slice's range-blocks.
        int x  = bid & 7;
        int q  = bid >> 3;
        range  = q % NR;
        slice  = (q / NR) * 8 + x;
    } else {
        range = bid % NR;
        slice = bid / NR;
    }
    int rbase = range * RBINS;
    int tid   = threadIdx.x;

    for (int i = tid; i < RBINS; i += PTHR) { s_all[i] = 0.f; s_evcnt[i] = 0u; }
    __syncthreads();

    float l_lr = 0.f;
    int   l_n  = 0;
    int begin = slice * CH;
    int end   = begin + CH; if (end > N) end = N;
    int span  = end - begin; if (span < 0) span = 0;
    int jmax  = span / STRIDE;

    const float* plr = lr + begin + tid * 8;
    const int*   ptm = tm + begin + tid * 8;
    const int*   pev = ev + begin + tid * 8;

    // expf + event bookkeeping only inside the owning range (1 of NR visits)
#define PROC1(T, L, E) {                                                  \
        unsigned rel_ = (unsigned)((T) - rbase);                          \
        if (rel_ < (unsigned)RBINS) {                                     \
            float r_ = __expf(L);                                         \
            atomicAdd(&s_all[rel_], r_);                                  \
            if ((E) != 0) {                                               \
                l_lr += (L); l_n++;                                       \
                unsigned enc_ = (1u << 28) + (unsigned)(r_ * 65536.0f + 0.5f); \
                atomicAdd(&s_evcnt[rel_], enc_);                          \
            }                                                             \
        } }

#define PROC8(TA, TB, LA, LB, EA, EB)                                    \
        PROC1(TA.x, LA.x, EA.x) PROC1(TA.y, LA.y, EA.y)                  \
        PROC1(TA.z, LA.z, EA.z) PROC1(TA.w, LA.w, EA.w)                  \
        PROC1(TB.x, LB.x, EB.x) PROC1(TB.y, LB.y, EB.y)                  \
        PROC1(TB.z, LB.z, EB.z) PROC1(TB.w, LB.w, EB.w)

#define LOADSLOT(TA, TB, LA, LB, EA, EB, OFF)                            \
        TA = *(const int4*)(ptm + (OFF));   TB = *(const int4*)(ptm + (OFF) + 4); \
        LA = *(const float4*)(plr + (OFF)); LB = *(const float4*)(plr + (OFF) + 4); \
        EA = *(const int4*)(pev + (OFF));   EB = *(const int4*)(pev + (OFF) + 4);

    int4 ta0, tb0, ea0, eb0; float4 la0, lb0;
    int4 ta1, tb1, ea1, eb1; float4 la1, lb1;
    if (jmax > 0) { LOADSLOT(ta0, tb0, la0, lb0, ea0, eb0, 0) }
    if (jmax > 1) { LOADSLOT(ta1, tb1, la1, lb1, ea1, eb1, STRIDE) }

    for (int j = 0; j < jmax; j += 2) {
        PROC8(ta0, tb0, la0, lb0, ea0, eb0)
        if (j + 2 < jmax) { int off = (j + 2) * STRIDE; LOADSLOT(ta0, tb0, la0, lb0, ea0, eb0, off) }
        if (j + 1 < jmax) {
            PROC8(ta1, tb1, la1, lb1, ea1, eb1)
            if (j + 3 < jmax) { int off = (j + 3) * STRIDE; LOADSLOT(ta1, tb1, la1, lb1, ea1, eb1, off) }
        }
    }
    for (int i = begin + jmax * STRIDE + tid; i < end; i += PTHR) {
        int T = tm[i]; float L = lr[i]; int E = ev[i];
        PROC1(T, L, E)
    }

    // per-block scalar partials (each event counted exactly once globally)
    int lane = tid & 63, wv = tid >> 6;
    #pragma unroll
    for (int off = 32; off > 0; off >>= 1) {
        l_lr += __shfl_down(l_lr, off, 64);
        l_n  += __shfl_down(l_n,  off, 64);
    }
    if (lane == 0) { red_f[wv] = l_lr; red_i[wv] = l_n; }
    __syncthreads();
    if (tid == 0) {
        float s = 0.f; int c = 0;
        #pragma unroll
        for (int w = 0; w < 16; ++w) { s += red_f[w]; c += red_i[w]; }
        ((float*)(ws + OFF_LRP))[bid] = s;
        ((int*)(ws + OFF_NP))[bid]   = c;
    }

    // non-atomic flush to this slice's private region
    float*    wa  = (float*)(ws + OFF_SLICE + (size_t)slice * PER_SLICE);
    unsigned* wec = (unsigned*)(ws + OFF_SLICE + (size_t)slice * PER_SLICE + (size_t)TBINS * 4);
    for (int i = tid; i < RBINS; i += PTHR) {
        wa[rbase + i]  = s_all[i];
        wec[rbase + i] = s_evcnt[i];
    }
}

// ---------------- fold NS slices; emit gsum; block 0 folds scalars ----------------
__global__ __launch_bounds__(256) void k_reduce(char* ws, int NS, int NB,
                                                float* all_g, float* ev_g, int* cnt_g,
                                                float* gsum, double* scal, int* nev) {
    __shared__ float lds[4];
    __shared__ float ldsf2[4];
    __shared__ int   ldsi2[4];
    int tid = threadIdx.x;
    int b = blockIdx.x * 256 + tid;
    float a = 0.f, d = 0.f; int c = 0;
    if (b < TBINS) {
        const char* base = ws + OFF_SLICE;
        for (int s = 0; s < NS; ++s) {
            const float*    wa  = (const float*)(base + (size_t)s * PER_SLICE);
            const unsigned* wec = (const unsigned*)(base + (size_t)s * PER_SLICE + (size_t)TBINS * 4);
            a += wa[b];
            unsigned e = wec[b];
            c += (int)(e >> 28);
            d += (float)(e & 0x0FFFFFFFu) * (1.0f / 65536.0f);
        }
        all_g[b] = a; ev_g[b] = d; cnt_g[b] = c;
    }
    int lane = tid & 63, wv = tid >> 6;
    float v = a;
    #pragma unroll
    for (int off = 32; off > 0; off >>= 1) v += __shfl_down(v, off, 64);
    if (lane == 0) lds[wv] = v;
    __syncthreads();
    if (tid == 0) {
        float s = 0.f;
        #pragma unroll
        for (int w = 0; w < 4; ++w) s += lds[w];
        gsum[blockIdx.x] = s;
    }

    if (blockIdx.x == 0) {
        float pl = 0.f; int pn = 0;
        for (int i = tid; i < NB; i += 256) {
            pl += ((const float*)(ws + OFF_LRP))[i];
            pn += ((const int*)(ws + OFF_NP))[i];
        }
        #pragma unroll
        for (int off = 32; off > 0; off >>= 1) {
            pl += __shfl_down(pl, off, 64);
            pn += __shfl_down(pn, off, 64);
        }
        if (lane == 0) { ldsf2[wv] = pl; ldsi2[wv] = pn; }
        __syncthreads();
        if (tid == 0) {
            float s = 0.f; int n = 0;
            #pragma unroll
            for (int w = 0; w < 4; ++w) { s += ldsf2[w]; n += ldsi2[w]; }
            scal[0] = (double)s;
            scal[1] = 0.0;
            *nev    = n;
        }
    }
}

// ---------------- per-bin Efron loss ----------------
__global__ __launch_bounds__(256) void k_loss(
        const float* __restrict__ all_g, const float* __restrict__ gsum,
        const int* __restrict__ cnt_g, const float* __restrict__ ev_g,
        double* scal) {
    __shared__ float lds_r[4];
    __shared__ float lds_s[4];
    __shared__ float sh_base;
    int b   = blockIdx.x;
    int tid = threadIdx.x;
    int t   = b * GROUP + tid;
    int lane = tid & 63, wv = tid >> 6;

    float gv = (tid < b) ? gsum[tid] : 0.f;
    float red = gv;
    #pragma unroll
    for (int off = 32; off > 0; off >>= 1) red += __shfl_down(red, off, 64);
    if (lane == 0) lds_r[wv] = red;
    __syncthreads();
    if (tid == 0) {
        float s = 0.f;
        #pragma unroll
        for (int w = 0; w < 4; ++w) s += lds_r[w];
        sh_base = s;
    }
    __syncthreads();
    float base = sh_base;

    float v = (t < TBINS) ? all_g[t] : 0.f;
    float x = v;
    #pragma unroll
    for (int off = 1; off < 64; off <<= 1) {
        float y = __shfl_up(x, off, 64);
        if (lane >= off) x += y;
    }
    if (lane == 63) lds_s[wv] = x;
    __syncthreads();
    float wbase = 0.f;
    for (int w = 0; w < wv; ++w) wbase += lds_s[w];
    float prefix = base + wbase + (x - v);

    float acc = 0.f;
    if (t < TBINS) {
        int n = cnt_g[t];
        if (n > 0) {
            float D  = ev_g[t];
            float nf = (float)n;
            float P  = D + (v - D) * (nf / (nf + 1.f));   // E[partial risk]
            float R  = prefix + P;
            for (int j = 0; j < n; ++j) {
                float arg = R - ((float)j / nf) * D + EPSF;
                acc += __logf(arg);
            }
        }
    }
    __syncthreads();
    #pragma unroll
    for (int off = 32; off > 0; off >>= 1) acc += __shfl_down(acc, off, 64);
    if (lane == 0) lds_r[wv] = acc;
    __syncthreads();
    if (tid == 0) {
        float s = 0.f;
        #pragma unroll
        for (int w = 0; w < 4; ++w) s += lds_r[w];
        atomicAdd(&scal[1], (double)s);
    }
}

__global__ void k_final(const double* __restrict__ scal,
                        const int* __restrict__ nev, float* out) {
    if (threadIdx.x == 0 && blockIdx.x == 0) {
        int n = *nev;
        double loss = (n > 0) ? (scal[1] - scal[0]) / (double)n : 0.0;
        out[0] = (float)loss;
    }
}

extern "C" void kernel_launch(void* const* d_in, const int* in_sizes, int n_in,
                              void* d_out, int out_size, void* d_ws, size_t ws_size,
                              hipStream_t stream) {
    const float* lr = (const float*)d_in[0];
    const int*   tm = (const int*)d_in[1];
    const int*   ev = (const int*)d_in[2];
    int N = in_sizes[0];

    char*   ws    = (char*)d_ws;
    float*  all_g = (float*)(ws + OFF_ALLG);
    float*  ev_g  = (float*)(ws + OFF_EVG);
    int*    cnt_g = (int*)(ws + OFF_CNTG);
    float*  gsum  = (float*)(ws + OFF_GSUM);
    double* scal  = (double*)(ws + OFF_SCAL);
    int*    nev   = (int*)(ws + OFF_NEV);

    size_t avail = (ws_size > (size_t)OFF_SLICE) ? ws_size - OFF_SLICE : 0;
    int NS = (int)(avail / PER_SLICE);
    if (NS > MAXNS) NS = MAXNS;
    if (NS >= 8) NS &= ~7;      // multiple of 8 enables the XCD swizzle
    if (NS < 1) NS = 1;
    int NB = NR * NS;           // <= 520
    int CH = (int)(((long long)N + (long long)NS * STRIDE - 1) / ((long long)NS * STRIDE)) * STRIDE;

    k_pass<<<NB, PTHR, 0, stream>>>(lr, tm, ev, N, NS, CH, ws);
    k_reduce<<<NGROUPS, 256, 0, stream>>>(ws, NS, NB, all_g, ev_g, cnt_g, gsum, scal, nev);
    k_loss<<<NGROUPS, 256, 0, stream>>>(all_g, gsum, cnt_g, ev_g, scal);
    k_final<<<1, 64, 0, stream>>>(scal, nev, (float*)d_out);
}

// Round 6
// 78.921 us; speedup vs baseline: 1.1879x; 1.1879x over previous
//
#include <hip/hip_runtime.h>
#include <hip/hip_fp16.h>
#include <math.h>

#define TBINS   50000
#define NR      4
#define RBINS   12500          // TBINS / NR
#define GROUP   256
#define NGROUPS 196            // ceil(TBINS / GROUP)
#define EPSF    1e-7f
#define PTHR    1024
#define STRIDE  (PTHR * 8)
#define MAXNS   64
#define NPREP   1024           // prep grid blocks (x256 thr)

// ---- ws layout (byte offsets; pack/slice regions computed at runtime) ----
#define OFF_ALLG  0            // f32[TBINS]
#define OFF_EVG   200000       // f32[TBINS]
#define OFF_CNTG  400000       // i32[TBINS]
#define OFF_GSUM  600000       // f32[NGROUPS] (pad 800)
#define OFF_SCAL  600800       // dbl[2]
#define OFF_NEV   600816       // int (pad to 600832)
#define OFF_LRP   600832       // f32[NPREP]
#define OFF_NP    604928       // i32[NPREP]
#define OFF_PACK  609024       // u32[N]
#define PER_SLICE 400000       // f32 wa[TBINS] + u32 wec[TBINS]

// ---------------- prep: pack (time<<16)|f16(exp(lr)) with event in sign bit ----------------
__global__ __launch_bounds__(256) void k_prep(
        const float* __restrict__ lr, const int* __restrict__ tm,
        const int* __restrict__ ev, int N, unsigned* __restrict__ packed,
        float* lrp, int* np) {
    __shared__ float red_f[4];
    __shared__ int   red_i[4];
    int tid = threadIdx.x;
    int gid = blockIdx.x * 256 + tid;
    const int T = NPREP * 256;
    float l_lr = 0.f;
    int   l_n  = 0;

#define PACK1(L, TT, E, OUT) {                                            \
        float r_ = __expf(L);                                             \
        unsigned hb_ = (unsigned)__half_as_ushort(__float2half(r_));      \
        if ((E) != 0) { hb_ |= 0x8000u; l_lr += (L); l_n++; }             \
        OUT = ((unsigned)(TT) << 16) | hb_; }

    int nvec = N & ~3;
    for (int base = gid * 4; base < nvec; base += T * 4) {
        float4 l4 = *(const float4*)(lr + base);
        int4   t4 = *(const int4*)(tm + base);
        int4   e4 = *(const int4*)(ev + base);
        uint4 o;
        PACK1(l4.x, t4.x, e4.x, o.x)
        PACK1(l4.y, t4.y, e4.y, o.y)
        PACK1(l4.z, t4.z, e4.z, o.z)
        PACK1(l4.w, t4.w, e4.w, o.w)
        *(uint4*)(packed + base) = o;
    }
    for (int i = nvec + gid; i < N; i += T) {
        unsigned o;
        PACK1(lr[i], tm[i], ev[i], o)
        packed[i] = o;
    }

    int lane = tid & 63, wv = tid >> 6;
    #pragma unroll
    for (int off = 32; off > 0; off >>= 1) {
        l_lr += __shfl_down(l_lr, off, 64);
        l_n  += __shfl_down(l_n,  off, 64);
    }
    if (lane == 0) { red_f[wv] = l_lr; red_i[wv] = l_n; }
    __syncthreads();
    if (tid == 0) {
        float s = 0.f; int c = 0;
        #pragma unroll
        for (int w = 0; w < 4; ++w) { s += red_f[w]; c += red_i[w]; }
        lrp[blockIdx.x] = s;
        np[blockIdx.x]  = c;
    }
}

// ---------------- histogram pass over packed u32 (4 B/elem) ----------------
__global__ __launch_bounds__(PTHR) void k_pass(
        const unsigned* __restrict__ packed, int N, int NS, int CH, char* slices) {
    __shared__ float    s_all[RBINS];
    __shared__ unsigned s_evcnt[RBINS];   // (count<<28) | fixed12.16(sum exp over events)

    int bid = blockIdx.x;
    int range, slice;
    if ((NS & 7) == 0) {
        // XCD-aware: hw assigns XCD = bid % 8; co-locate a slice's 4 range-blocks.
        int x  = bid & 7;
        int q  = bid >> 3;
        range  = q & 3;
        slice  = (q >> 2) * 8 + x;
    } else {
        range = bid & 3;
        slice = bid >> 2;
    }
    unsigned rbase = (unsigned)(range * RBINS);
    int tid = threadIdx.x;

    for (int i = tid; i < RBINS; i += PTHR) { s_all[i] = 0.f; s_evcnt[i] = 0u; }
    __syncthreads();

    int begin = slice * CH;
    int end   = begin + CH; if (end > N) end = N;
    int span  = end - begin; if (span < 0) span = 0;
    int jmax  = span / STRIDE;

    const unsigned* pp = packed + begin + tid * 8;

#define PROC1(P) {                                                        \
        unsigned rel_ = ((P) >> 16) - rbase;                              \
        if (rel_ < (unsigned)RBINS) {                                     \
            float r_ = __half2float(__ushort_as_half((unsigned short)((P) & 0x7FFFu))); \
            atomicAdd(&s_all[rel_], r_);                                  \
            if ((P) & 0x8000u) {                                          \
                unsigned enc_ = (1u << 28) + (unsigned)(r_ * 65536.0f + 0.5f); \
                atomicAdd(&s_evcnt[rel_], enc_);                          \
            }                                                             \
        } }

#define PROC8(A, B)                                                      \
        PROC1(A.x) PROC1(A.y) PROC1(A.z) PROC1(A.w)                      \
        PROC1(B.x) PROC1(B.y) PROC1(B.z) PROC1(B.w)

    uint4 a0, b0, a1, b1;
    if (jmax > 0) { a0 = *(const uint4*)pp; b0 = *(const uint4*)(pp + 4); }
    if (jmax > 1) { a1 = *(const uint4*)(pp + STRIDE); b1 = *(const uint4*)(pp + STRIDE + 4); }

    for (int j = 0; j < jmax; j += 2) {
        PROC8(a0, b0)
        if (j + 2 < jmax) {
            a0 = *(const uint4*)(pp + (j + 2) * STRIDE);
            b0 = *(const uint4*)(pp + (j + 2) * STRIDE + 4);
        }
        if (j + 1 < jmax) {
            PROC8(a1, b1)
            if (j + 3 < jmax) {
                a1 = *(const uint4*)(pp + (j + 3) * STRIDE);
                b1 = *(const uint4*)(pp + (j + 3) * STRIDE + 4);
            }
        }
    }
    for (int i = begin + jmax * STRIDE + tid; i < end; i += PTHR) {
        unsigned P = packed[i];
        PROC1(P)
    }
    __syncthreads();   // all atomics done before flush

    float*    wa  = (float*)(slices + (size_t)slice * PER_SLICE);
    unsigned* wec = (unsigned*)(slices + (size_t)slice * PER_SLICE + (size_t)TBINS * 4);
    for (int i = tid; i < RBINS; i += PTHR) {
        wa[rbase + i]  = s_all[i];
        wec[rbase + i] = s_evcnt[i];
    }
}

// ---------------- fold NS slices; emit gsum; block 0 folds prep scalars ----------------
__global__ __launch_bounds__(256) void k_reduce(const char* __restrict__ slices, int NS,
                                                const float* __restrict__ lrp,
                                                const int* __restrict__ np,
                                                float* all_g, float* ev_g, int* cnt_g,
                                                float* gsum, double* scal, int* nev) {
    __shared__ float lds[4];
    __shared__ float ldsf2[4];
    __shared__ int   ldsi2[4];
    int tid = threadIdx.x;
    int b = blockIdx.x * 256 + tid;
    float a = 0.f, d = 0.f; int c = 0;
    if (b < TBINS) {
        for (int s = 0; s < NS; ++s) {
            const float*    wa  = (const float*)(slices + (size_t)s * PER_SLICE);
            const unsigned* wec = (const unsigned*)(slices + (size_t)s * PER_SLICE + (size_t)TBINS * 4);
            a += wa[b];
            unsigned e = wec[b];
            c += (int)(e >> 28);
            d += (float)(e & 0x0FFFFFFFu) * (1.0f / 65536.0f);
        }
        all_g[b] = a; ev_g[b] = d; cnt_g[b] = c;
    }
    int lane = tid & 63, wv = tid >> 6;
    float v = a;
    #pragma unroll
    for (int off = 32; off > 0; off >>= 1) v += __shfl_down(v, off, 64);
    if (lane == 0) lds[wv] = v;
    __syncthreads();
    if (tid == 0) {
        float s = 0.f;
        #pragma unroll
        for (int w = 0; w < 4; ++w) s += lds[w];
        gsum[blockIdx.x] = s;
    }

    if (blockIdx.x == 0) {
        float pl = 0.f; int pn = 0;
        for (int i = tid; i < NPREP; i += 256) { pl += lrp[i]; pn += np[i]; }
        #pragma unroll
        for (int off = 32; off > 0; off >>= 1) {
            pl += __shfl_down(pl, off, 64);
            pn += __shfl_down(pn, off, 64);
        }
        if (lane == 0) { ldsf2[wv] = pl; ldsi2[wv] = pn; }
        __syncthreads();
        if (tid == 0) {
            float s = 0.f; int n = 0;
            #pragma unroll
            for (int w = 0; w < 4; ++w) { s += ldsf2[w]; n += ldsi2[w]; }
            scal[0] = (double)s;
            scal[1] = 0.0;
            *nev    = n;
        }
    }
}

// ---------------- per-bin Efron loss ----------------
__global__ __launch_bounds__(256) void k_loss(
        const float* __restrict__ all_g, const float* __restrict__ gsum,
        const int* __restrict__ cnt_g, const float* __restrict__ ev_g,
        double* scal) {
    __shared__ float lds_r[4];
    __shared__ float lds_s[4];
    __shared__ float sh_base;
    int b   = blockIdx.x;
    int tid = threadIdx.x;
    int t   = b * GROUP + tid;
    int lane = tid & 63, wv = tid >> 6;

    float gv = (tid < b) ? gsum[tid] : 0.f;
    float red = gv;
    #pragma unroll
    for (int off = 32; off > 0; off >>= 1) red += __shfl_down(red, off, 64);
    if (lane == 0) lds_r[wv] = red;
    __syncthreads();
    if (tid == 0) {
        float s = 0.f;
        #pragma unroll
        for (int w = 0; w < 4; ++w) s += lds_r[w];
        sh_base = s;
    }
    __syncthreads();
    float base = sh_base;

    float v = (t < TBINS) ? all_g[t] : 0.f;
    float x = v;
    #pragma unroll
    for (int off = 1; off < 64; off <<= 1) {
        float y = __shfl_up(x, off, 64);
        if (lane >= off) x += y;
    }
    if (lane == 63) lds_s[wv] = x;
    __syncthreads();
    float wbase = 0.f;
    for (int w = 0; w < wv; ++w) wbase += lds_s[w];
    float prefix = base + wbase + (x - v);

    float acc = 0.f;
    if (t < TBINS) {
        int n = cnt_g[t];
        if (n > 0) {
            float D  = ev_g[t];
            float nf = (float)n;
            float P  = D + (v - D) * (nf / (nf + 1.f));   // E[partial risk]
            float R  = prefix + P;
            for (int j = 0; j < n; ++j) {
                float arg = R - ((float)j / nf) * D + EPSF;
                acc += __logf(arg);
            }
        }
    }
    __syncthreads();
    #pragma unroll
    for (int off = 32; off > 0; off >>= 1) acc += __shfl_down(acc, off, 64);
    if (lane == 0) lds_r[wv] = acc;
    __syncthreads();
    if (tid == 0) {
        float s = 0.f;
        #pragma unroll
        for (int w = 0; w < 4; ++w) s += lds_r[w];
        atomicAdd(&scal[1], (double)s);
    }
}

__global__ void k_final(const double* __restrict__ scal,
                        const int* __restrict__ nev, float* out) {
    if (threadIdx.x == 0 && blockIdx.x == 0) {
        int n = *nev;
        double loss = (n > 0) ? (scal[1] - scal[0]) / (double)n : 0.0;
        out[0] = (float)loss;
    }
}

extern "C" void kernel_launch(void* const* d_in, const int* in_sizes, int n_in,
                              void* d_out, int out_size, void* d_ws, size_t ws_size,
                              hipStream_t stream) {
    const float* lr = (const float*)d_in[0];
    const int*   tm = (const int*)d_in[1];
    const int*   ev = (const int*)d_in[2];
    int N = in_sizes[0];

    char*     ws     = (char*)d_ws;
    float*    all_g  = (float*)(ws + OFF_ALLG);
    float*    ev_g   = (float*)(ws + OFF_EVG);
    int*      cnt_g  = (int*)(ws + OFF_CNTG);
    float*    gsum   = (float*)(ws + OFF_GSUM);
    double*   scal   = (double*)(ws + OFF_SCAL);
    int*      nev    = (int*)(ws + OFF_NEV);
    float*    lrp    = (float*)(ws + OFF_LRP);
    int*      np     = (int*)(ws + OFF_NP);
    unsigned* packed = (unsigned*)(ws + OFF_PACK);

    size_t off_slice = ((size_t)OFF_PACK + (size_t)N * 4 + 255) & ~(size_t)255;
    char*  slices    = ws + off_slice;

    size_t avail = (ws_size > off_slice) ? ws_size - off_slice : 0;
    int NS = (int)(avail / PER_SLICE);
    if (NS > MAXNS) NS = MAXNS;
    if (NS >= 8) NS &= ~7;      // multiple of 8 enables the XCD swizzle
    if (NS < 1) NS = 1;
    int NB = NR * NS;           // 256 at NS=64 -> exactly one scheduling round
    int CH = (int)(((long long)N + (long long)NS * STRIDE - 1) / ((long long)NS * STRIDE)) * STRIDE;

    k_prep<<<NPREP, 256, 0, stream>>>(lr, tm, ev, N, packed, lrp, np);
    k_pass<<<NB, PTHR, 0, stream>>>(packed, N, NS, CH, slices);
    k_reduce<<<NGROUPS, 256, 0, stream>>>(slices, NS, lrp, np, all_g, ev_g, cnt_g, gsum, scal, nev);
    k_loss<<<NGROUPS, 256, 0, stream>>>(all_g, gsum, cnt_g, ev_g, scal);
    k_final<<<1, 64, 0, stream>>>(scal, nev, (float*)d_out);
}